// Round 13
// baseline (82.937 us; speedup 1.0000x reference)
//
#include <hip/hip_runtime.h>
#include <hip/hip_fp16.h>

// Problem constants (fixed by reference setup_inputs()).
#define BB 8
#define CC 256
#define EE 18000
#define TT 4500
#define BT (BB * TT)     // 36000
#define BE (BB * EE)     // 144000
#define NT 1024          // pool threads (16 waves); 73.9KB LDS -> 2 blocks/CU = 100% occ
#define GPAD 18432       // padded per-batch gidx16 stride (pool reads up to 18431)

// ---------------- setup ----------------------------------------------------

// zero counts[BT] and wmask[BB*1024] (adjacent in ws)
__global__ void zero_kernel(int* __restrict__ p) {
    int i = blockIdx.x * blockDim.x + threadIdx.x;
    if (i < BT + BB * 1024) p[i] = 0;
}

__global__ void count_kernel(const int* __restrict__ gid, int* __restrict__ counts) {
    int i = blockIdx.x * blockDim.x + threadIdx.x;
    if (i < BE) {
        int b = i / EE;
        atomicAdd(&counts[b * TT + gid[i]], 1);
    }
}

// one block per batch: exclusive scan of counts -> off32 (group starts),
// cursor (scatter cursor, base b*EE), gidx16[pos] = group whose end-1 == pos,
// wmask[b][window] bit k set iff position 18*window+k is a group end-1.
__global__ __launch_bounds__(1024) void scan_kernel(const int* __restrict__ counts,
                                                    int* __restrict__ cursor,
                                                    int* __restrict__ off32,
                                                    unsigned short* __restrict__ gidx16,
                                                    unsigned int* __restrict__ wmask) {
    __shared__ int part[1024];
    const int b = blockIdx.x;
    const int t = threadIdx.x;
    const int CHUNK = 5;                          // 1024*5 >= 4500
    int lo = t * CHUNK; if (lo > TT) lo = TT;
    int hi = lo + CHUNK; if (hi > TT) hi = TT;
    int s = 0;
    for (int i = lo; i < hi; ++i) s += counts[b * TT + i];
    part[t] = s;
    __syncthreads();
    for (int d = 1; d < 1024; d <<= 1) {
        int v = (t >= d) ? part[t - d] : 0;
        __syncthreads();
        part[t] += v;
        __syncthreads();
    }
    int run = part[t] - s;                        // per-batch exclusive prefix
    for (int i = lo; i < hi; ++i) {
        int cnt = counts[b * TT + i];
        off32[b * TT + i]  = run;
        cursor[b * TT + i] = b * EE + run;
        int en = run + cnt;
        if (cnt) {
            int ep = en - 1;                      // end position of group i
            gidx16[b * GPAD + ep] = (unsigned short)i;
            atomicOr(&wmask[(b << 10) + ep / 18], 1u << (ep % 18));
        }
        run = en;
    }
}

// per-group epilogue table: tabJ[g] = {jprev (0xFFFF if start==0), bits(inv)}
// jprev = group whose end == this group's start (lookup via gidx16).
__global__ void table_kernel(const int* __restrict__ counts,
                             const int* __restrict__ off32,
                             const unsigned short* __restrict__ gidx16,
                             uint2* __restrict__ tabJ) {
    int i = blockIdx.x * blockDim.x + threadIdx.x;
    if (i < BT) {
        int b   = i / TT;
        int st  = off32[i];
        int cnt = counts[i];
        unsigned jp  = st ? (unsigned)gidx16[b * GPAD + st - 1] : 0xFFFFu;
        float    inv = cnt ? 1.0f / (float)cnt : 0.0f;
        tabJ[i] = make_uint2(jp, __float_as_uint(inv));
    }
}

// atomic CSR scatter: prank16[e] = raw CSR position of edge e in batch b
__global__ void scatter_kernel(const int* __restrict__ gid,
                               int* __restrict__ cursor,
                               unsigned short* __restrict__ prank16) {
    int i = blockIdx.x * blockDim.x + threadIdx.x;
    if (i < BE) {
        int b = i / EE;
        int p = atomicAdd(&cursor[b * TT + gid[i]], 1) - b * EE;
        prank16[i] = (unsigned short)p;           // < 18000
    }
}

// ---------------- main: 2 channels/block, half2 values, compact prefix -----
// One block per (b, channel-pair), 1024 threads, 73.9KB LDS -> 2 blocks/CU.
// Scatter: ONE random ds_write_b32 (__half2{c0,c1}) per edge serves both
// channels. Phase A: 9x b64 reads = 2 positions x 2 channels; fp32 dual
// prefix + dual shfl scan. Phase C: write float2{P0,P1} ONLY at group-end
// positions into compact[g] (region aliases smem[0..4607]; safe: raw values
// consumed into pv registers before the barrier). Epilogue: out[g] =
// (C[g]-C[jprev])*inv, C reads near-coalesced. Threads >= 1000: wmask=0 ->
// no stray compact writes; their pv/wsum[15] garbage never consumed.

__global__ __launch_bounds__(1024, 8) void pool_kernel(const float* __restrict__ fe,
                                                       const unsigned short* __restrict__ prank16,
                                                       const unsigned short* __restrict__ gidx16,
                                                       const unsigned int* __restrict__ wmask,
                                                       const uint2* __restrict__ tabJ,
                                                       float* __restrict__ out) {
    __shared__ float2 smem[NT * 9];               // 73728 B: half2[18432] / compact float2[4608]
    __shared__ float2 wsum[16];
    const int b   = blockIdx.x >> 7;              // 128 channel-pairs per batch
    const int c0  = (blockIdx.x & 127) << 1;
    const int tid = threadIdx.x;
    const int wv  = tid >> 6;
    const int ln  = tid & 63;

    // scatter both channels into CSR order as half2 (one b32 write per edge)
    __half2* h2 = reinterpret_cast<__half2*>(smem);
    const float4*  feA = (const float4*)(fe + (size_t)(b * CC + c0) * EE);
    const float4*  feB = feA + (EE / 4);          // channel c0+1 row
    const ushort4* rk4 = (const ushort4*)(prank16 + (size_t)b * EE);
#pragma unroll
    for (int i = 0; i < 5; ++i) {                 // 5*1024 = 5120 >= 4500
        int idx = tid + (i << 10);
        if (idx < EE / 4) {
            float4  va = feA[idx];
            float4  vb = feB[idx];
            ushort4 r  = rk4[idx];
            h2[r.x] = __floats2half2_rn(va.x, vb.x);
            h2[r.y] = __floats2half2_rn(va.y, vb.y);
            h2[r.z] = __floats2half2_rn(va.z, vb.z);
            h2[r.w] = __floats2half2_rn(va.w, vb.w);
        }
    }
    __syncthreads();

    // phase A: 9x b64 reads = positions {2k, 2k+1} x channels {c0, c1}
    const int fbase = 9 * tid;                    // float2 index; 72B stride
    float4 pv[9];                                 // {v2k.c0, v2k.c1, pfx2k1.c0, pfx2k1.c1}
#pragma unroll
    for (int k = 0; k < 9; ++k) {
        float2 f = smem[fbase + k];
        __half2 ha = *reinterpret_cast<const __half2*>(&f.x);  // pos 2k
        __half2 hb = *reinterpret_cast<const __half2*>(&f.y);  // pos 2k+1
        float2 va = __half22float2(ha);
        float2 vb = __half22float2(hb);
        pv[k] = make_float4(va.x, va.y, va.x + vb.x, va.y + vb.y);
    }
    float tx0 = pv[0].z + pv[1].z, tx1 = pv[2].z + pv[3].z;
    float tx2 = pv[4].z + pv[5].z, tx3 = pv[6].z + pv[7].z;
    float ty0 = pv[0].w + pv[1].w, ty1 = pv[2].w + pv[3].w;
    float ty2 = pv[4].w + pv[5].w, ty3 = pv[6].w + pv[7].w;
    const float sumx = ((tx0 + tx1) + (tx2 + tx3)) + pv[8].z;
    const float sumy = ((ty0 + ty1) + (ty2 + ty3)) + pv[8].w;

    // dual per-wave inclusive shfl scan of window sums
    float scx = sumx, scy = sumy;
#pragma unroll
    for (int d = 1; d < 64; d <<= 1) {
        float ox = __shfl_up(scx, d, 64);
        float oy = __shfl_up(scy, d, 64);
        if (ln >= d) { scx += ox; scy += oy; }
    }
    if (ln == 63) wsum[wv] = make_float2(scx, scy);
    __syncthreads();

    float crx = 0.0f, cry = 0.0f;
#pragma unroll
    for (int j = 0; j < 16; ++j) {
        float2 tw = wsum[j];
        if (j < wv) { crx += tw.x; cry += tw.y; }
    }

    // phase C: masked compact writes of end prefixes (aliases smem head)
    const unsigned int  mask = wmask[(b << 10) + tid];
    const unsigned int* gx   = (const unsigned int*)(gidx16 + b * GPAD);
    float runx = crx + (scx - sumx);              // exclusive prefix of window
    float runy = cry + (scy - sumy);
#pragma unroll
    for (int k = 0; k < 9; ++k) {
        unsigned gpair = gx[fbase + k];           // gidx at pos 2k (lo), 2k+1 (hi)
        float ax = runx + pv[k].x, ay = runy + pv[k].y;   // prefix at pos 2k
        float bx = runx + pv[k].z, by = runy + pv[k].w;   // prefix at pos 2k+1
        if (mask & (1u << (2 * k)))     smem[gpair & 0xffffu] = make_float2(ax, ay);
        if (mask & (1u << (2 * k + 1))) smem[gpair >> 16]     = make_float2(bx, by);
        runx = bx; runy = by;
    }
    __syncthreads();

    // epilogue: 4 consecutive groups per slot; both channels per C read
    const uint2* tb    = tabJ + b * TT;
    float*       outb0 = out + (size_t)(b * CC + c0) * TT;
    float*       outb1 = outb0 + TT;
    for (int s = tid; s < TT / 4; s += NT) {      // 1125 slots
        uint4 qA = *reinterpret_cast<const uint4*>(tb + (s << 2));
        uint4 qB = *reinterpret_cast<const uint4*>(tb + (s << 2) + 2);
        float4 o0, o1;
#pragma unroll
        for (int j = 0; j < 4; ++j) {
            unsigned jpw = (j == 0) ? qA.x : (j == 1) ? qA.z : (j == 2) ? qB.x : qB.z;
            unsigned ivw = (j == 0) ? qA.y : (j == 1) ? qA.w : (j == 2) ? qB.y : qB.w;
            int g = (s << 2) + j;
            float2 Ca = smem[g];
            unsigned jp = jpw & 0xffffu;
            float2 Cb = (jp != 0xffffu) ? smem[jp] : make_float2(0.f, 0.f);
            float inv = __uint_as_float(ivw);
            float vx = (inv != 0.0f) ? (Ca.x - Cb.x) * inv : 0.0f;
            float vy = (inv != 0.0f) ? (Ca.y - Cb.y) * inv : 0.0f;
            (&o0.x)[j] = vx;
            (&o1.x)[j] = vy;
        }
        *reinterpret_cast<float4*>(outb0 + (s << 2)) = o0;
        *reinterpret_cast<float4*>(outb1 + (s << 2)) = o1;
    }
}

extern "C" void kernel_launch(void* const* d_in, const int* in_sizes, int n_in,
                              void* d_out, int out_size, void* d_ws, size_t ws_size,
                              hipStream_t stream) {
    const float* fe  = (const float*)d_in[0];
    const int*   gid = (const int*)d_in[1];
    float*       out = (float*)d_out;

    // ws: counts[BT] i32 | wmask[BB*1024] u32 | cursor[BT] i32 | off32[BT] i32 |
    //     tabJ[BT] uint2 | gidx16[BB*GPAD] u16 | prank16[BE] u16
    int*            counts  = (int*)d_ws;
    unsigned int*   wmask   = (unsigned int*)(counts + BT);
    int*            cursor  = (int*)(wmask + BB * 1024);
    int*            off32   = cursor + BT;
    uint2*          tabJ    = (uint2*)(off32 + BT);        // 8B-aligned
    unsigned short* gidx16  = (unsigned short*)(tabJ + BT);
    unsigned short* prank16 = gidx16 + BB * GPAD;

    zero_kernel<<<(BT + BB * 1024 + 255) / 256, 256, 0, stream>>>(counts);
    count_kernel<<<(BE + 255) / 256, 256, 0, stream>>>(gid, counts);
    scan_kernel<<<BB, 1024, 0, stream>>>(counts, cursor, off32, gidx16, wmask);
    table_kernel<<<(BT + 255) / 256, 256, 0, stream>>>(counts, off32, gidx16, tabJ);
    scatter_kernel<<<(BE + 255) / 256, 256, 0, stream>>>(gid, cursor, prank16);
    pool_kernel<<<BB * (CC / 2), 1024, 0, stream>>>(fe, prank16, gidx16, wmask, tabJ, out);
}

// Round 14
// 78.795 us; speedup vs baseline: 1.0526x; 1.0526x over previous
//
#include <hip/hip_runtime.h>
#include <hip/hip_fp16.h>

// Problem constants (fixed by reference setup_inputs()).
#define BB 8
#define CC 256
#define EE 18000
#define TT 4500
#define BT (BB * TT)     // 36000
#define BE (BB * EE)     // 144000
#define NT 1024          // pool threads (16 waves); ~74KB LDS -> 2 blocks/CU
#define GT (9 * 1024)    // u32 words per batch in transposed gidx table

// ---------------- setup ----------------------------------------------------

// zero counts[BT] and gidxT32[BB*GT] (adjacent in ws)
__global__ void zero_kernel(int* __restrict__ p) {
    int i = blockIdx.x * blockDim.x + threadIdx.x;
    if (i < BT + BB * GT) p[i] = 0;
}

__global__ void count_kernel(const int* __restrict__ gid, int* __restrict__ counts) {
    int i = blockIdx.x * blockDim.x + threadIdx.x;
    if (i < BE) {
        int b = i / EE;
        atomicAdd(&counts[b * TT + gid[i]], 1);
    }
}

// one block per batch: exclusive scan of counts -> off32 (group starts),
// cursor (scatter cursor), gidx16[pos]=g for end positions (plain), and the
// TRANSPOSED flag table gidxT16[b][j][t*2+half] = 0x8000|g at end positions
// (zero elsewhere) so pool's phase C reads are coalesced u32 loads.
__global__ __launch_bounds__(1024) void scan_kernel(const int* __restrict__ counts,
                                                    int* __restrict__ cursor,
                                                    int* __restrict__ off32,
                                                    unsigned short* __restrict__ gidx16,
                                                    unsigned short* __restrict__ gidxT16) {
    __shared__ int part[1024];
    const int b = blockIdx.x;
    const int t = threadIdx.x;
    const int CHUNK = 5;                          // 1024*5 >= 4500
    int lo = t * CHUNK; if (lo > TT) lo = TT;
    int hi = lo + CHUNK; if (hi > TT) hi = TT;
    int s = 0;
    for (int i = lo; i < hi; ++i) s += counts[b * TT + i];
    part[t] = s;
    __syncthreads();
    for (int d = 1; d < 1024; d <<= 1) {
        int v = (t >= d) ? part[t - d] : 0;
        __syncthreads();
        part[t] += v;
        __syncthreads();
    }
    int run = part[t] - s;                        // per-batch exclusive prefix
    for (int i = lo; i < hi; ++i) {
        int cnt = counts[b * TT + i];
        off32[b * TT + i]  = run;
        cursor[b * TT + i] = b * EE + run;
        int en = run + cnt;
        if (cnt) {
            int ep = en - 1;                      // end position of group i
            gidx16[b * EE + ep] = (unsigned short)i;
            int wt = ep / 18, k = ep % 18;
            gidxT16[((b * 9 + (k >> 1)) * 1024 + wt) * 2 + (k & 1)] =
                (unsigned short)(0x8000u | (unsigned)i);
        }
        run = en;
    }
}

// per-group epilogue table: tabJ[g] = {jprev (0xFFFF if start==0), bits(inv)}
__global__ void table_kernel(const int* __restrict__ counts,
                             const int* __restrict__ off32,
                             const unsigned short* __restrict__ gidx16,
                             uint2* __restrict__ tabJ) {
    int i = blockIdx.x * blockDim.x + threadIdx.x;
    if (i < BT) {
        int b   = i / TT;
        int st  = off32[i];
        int cnt = counts[i];
        unsigned jp  = st ? (unsigned)gidx16[b * EE + st - 1] : 0xFFFFu;
        float    inv = cnt ? 1.0f / (float)cnt : 0.0f;
        tabJ[i] = make_uint2(jp, __float_as_uint(inv));
    }
}

// atomic CSR scatter: prank16[e] = raw CSR position of edge e in batch b
__global__ void scatter_kernel(const int* __restrict__ gid,
                               int* __restrict__ cursor,
                               unsigned short* __restrict__ prank16) {
    int i = blockIdx.x * blockDim.x + threadIdx.x;
    if (i < BE) {
        int b = i / EE;
        int p = atomicAdd(&cursor[b * TT + gid[i]], 1) - b * EE;
        prank16[i] = (unsigned short)p;           // < 18000
    }
}

// ---------------- main: 2 channels/block, half2 values, compact prefix -----
// One block per (b, channel-pair), 1024 threads, ~74KB LDS -> 2 blocks/CU.
// Scatter: ONE random ds_write_b32 (half2{c0,c1}) per edge serves both
// channels. Phase A: 9x b64 reads (2 positions x 2 channels) -> pv regs.
// Phase C: coalesced u32 gidxT loads; write float2 end-prefixes into the
// compact region (aliases smem head; safe: values live in pv before the
// barrier). Epilogue: fully scalar-unrolled (NO dynamic vector-component
// indexing -> no scratch spill, R13's bug), out[g]=(C[g]-C[jprev])*inv.

__global__ __launch_bounds__(1024, 8) void pool_kernel(const float* __restrict__ fe,
                                                       const unsigned short* __restrict__ prank16,
                                                       const unsigned int* __restrict__ gidxT32,
                                                       const uint2* __restrict__ tabJ,
                                                       float* __restrict__ out) {
    __shared__ float2 smem[NT * 9];               // 73728 B; half2 view = [18432]
    __shared__ float2 wsum[16];
    const int b   = blockIdx.x >> 7;              // 128 channel-pairs per batch
    const int c0  = (blockIdx.x & 127) << 1;
    const int tid = threadIdx.x;
    const int wv  = tid >> 6;
    const int ln  = tid & 63;

    // scatter both channels into CSR order as half2 (one b32 write per edge)
    __half2* h2 = reinterpret_cast<__half2*>(smem);
    const float4*  feA = (const float4*)(fe + (size_t)(b * CC + c0) * EE);
    const float4*  feB = feA + (EE / 4);          // channel c0+1 row
    const ushort4* rk4 = (const ushort4*)(prank16 + (size_t)b * EE);
#pragma unroll
    for (int i = 0; i < 5; ++i) {                 // 5*1024 = 5120 >= 4500
        int idx = tid + (i << 10);
        if (idx < EE / 4) {
            float4  va = feA[idx];
            float4  vb = feB[idx];
            ushort4 r  = rk4[idx];
            h2[r.x] = __floats2half2_rn(va.x, vb.x);
            h2[r.y] = __floats2half2_rn(va.y, vb.y);
            h2[r.z] = __floats2half2_rn(va.z, vb.z);
            h2[r.w] = __floats2half2_rn(va.w, vb.w);
        }
    }
    __syncthreads();

    // phase A: 9x b64 reads = positions {2k,2k+1} x channels {c0,c1}
    const int fbase = 9 * tid;                    // float2 index; 72B stride
    float4 pv[9];                                 // {v2k.x, v2k.y, pfx2k1.x, pfx2k1.y}
#pragma unroll
    for (int k = 0; k < 9; ++k) {
        float2 f = smem[fbase + k];
        __half2 ha = *reinterpret_cast<const __half2*>(&f.x);  // pos 2k
        __half2 hb = *reinterpret_cast<const __half2*>(&f.y);  // pos 2k+1
        float2 va = __half22float2(ha);
        float2 vb = __half22float2(hb);
        pv[k] = make_float4(va.x, va.y, va.x + vb.x, va.y + vb.y);
    }
    float tx0 = pv[0].z + pv[1].z, tx1 = pv[2].z + pv[3].z;
    float tx2 = pv[4].z + pv[5].z, tx3 = pv[6].z + pv[7].z;
    float ty0 = pv[0].w + pv[1].w, ty1 = pv[2].w + pv[3].w;
    float ty2 = pv[4].w + pv[5].w, ty3 = pv[6].w + pv[7].w;
    const float sumx = ((tx0 + tx1) + (tx2 + tx3)) + pv[8].z;
    const float sumy = ((ty0 + ty1) + (ty2 + ty3)) + pv[8].w;

    // dual per-wave inclusive shfl scan of window sums
    float scx = sumx, scy = sumy;
#pragma unroll
    for (int d = 1; d < 64; d <<= 1) {
        float ox = __shfl_up(scx, d, 64);
        float oy = __shfl_up(scy, d, 64);
        if (ln >= d) { scx += ox; scy += oy; }
    }
    if (ln == 63) wsum[wv] = make_float2(scx, scy);
    __syncthreads();

    float crx = 0.0f, cry = 0.0f;
#pragma unroll
    for (int j = 0; j < 16; ++j) {
        float2 tw = wsum[j];
        if (j < wv) { crx += tw.x; cry += tw.y; }
    }

    // phase C: coalesced gidxT loads; masked compact end-prefix writes
    const unsigned int* gxT = gidxT32 + b * GT;
    float runx = crx + (scx - sumx);              // exclusive prefix of window
    float runy = cry + (scy - sumy);
#pragma unroll
    for (int k = 0; k < 9; ++k) {
        unsigned w = gxT[(k << 10) + tid];        // lo16: pos 2k, hi16: pos 2k+1
        float ax = runx + pv[k].x, ay = runy + pv[k].y;
        float bx = runx + pv[k].z, by = runy + pv[k].w;
        if (w & 0x8000u)     smem[w & 0x7fffu]         = make_float2(ax, ay);
        if (w & 0x80000000u) smem[(w >> 16) & 0x7fffu] = make_float2(bx, by);
        runx = bx; runy = by;
    }
    __syncthreads();

    // epilogue: 4 consecutive groups per slot; fully scalar-unrolled
    const uint2* tb    = tabJ + b * TT;
    float*       outb0 = out + (size_t)(b * CC + c0) * TT;
    float*       outb1 = outb0 + TT;
    for (int s = tid; s < TT / 4; s += NT) {      // 1125 slots
        int base4 = s << 2;
        uint4 qA = *reinterpret_cast<const uint4*>(tb + base4);      // jp0,iv0,jp1,iv1
        uint4 qB = *reinterpret_cast<const uint4*>(tb + base4 + 2);  // jp2,iv2,jp3,iv3

        float2 C0 = smem[base4 + 0];
        float2 C1 = smem[base4 + 1];
        float2 C2 = smem[base4 + 2];
        float2 C3 = smem[base4 + 3];
        float2 Z  = make_float2(0.f, 0.f);
        float2 B0 = (qA.x != 0xFFFFu) ? smem[qA.x] : Z;
        float2 B1 = (qA.z != 0xFFFFu) ? smem[qA.z] : Z;
        float2 B2 = (qB.x != 0xFFFFu) ? smem[qB.x] : Z;
        float2 B3 = (qB.z != 0xFFFFu) ? smem[qB.z] : Z;
        float iv0 = __uint_as_float(qA.y), iv1 = __uint_as_float(qA.w);
        float iv2 = __uint_as_float(qB.y), iv3 = __uint_as_float(qB.w);

        float4 o0, o1;
        o0.x = (C0.x - B0.x) * iv0;  o1.x = (C0.y - B0.y) * iv0;
        o0.y = (C1.x - B1.x) * iv1;  o1.y = (C1.y - B1.y) * iv1;
        o0.z = (C2.x - B2.x) * iv2;  o1.z = (C2.y - B2.y) * iv2;
        o0.w = (C3.x - B3.x) * iv3;  o1.w = (C3.y - B3.y) * iv3;

        *reinterpret_cast<float4*>(outb0 + base4) = o0;
        *reinterpret_cast<float4*>(outb1 + base4) = o1;
    }
}

extern "C" void kernel_launch(void* const* d_in, const int* in_sizes, int n_in,
                              void* d_out, int out_size, void* d_ws, size_t ws_size,
                              hipStream_t stream) {
    const float* fe  = (const float*)d_in[0];
    const int*   gid = (const int*)d_in[1];
    float*       out = (float*)d_out;

    // ws: counts[BT] i32 | gidxT32[BB*GT] u32 | cursor[BT] i32 | off32[BT] i32 |
    //     tabJ[BT] uint2 | gidx16[BB*EE] u16 | prank16[BE] u16
    int*            counts  = (int*)d_ws;
    unsigned int*   gidxT32 = (unsigned int*)(counts + BT);
    int*            cursor  = (int*)(gidxT32 + BB * GT);
    int*            off32   = cursor + BT;
    uint2*          tabJ    = (uint2*)(off32 + BT);
    unsigned short* gidx16  = (unsigned short*)(tabJ + BT);
    unsigned short* prank16 = gidx16 + (size_t)BB * EE;

    zero_kernel<<<(BT + BB * GT + 255) / 256, 256, 0, stream>>>(counts);
    count_kernel<<<(BE + 255) / 256, 256, 0, stream>>>(gid, counts);
    scan_kernel<<<BB, 1024, 0, stream>>>(counts, cursor, off32, gidx16,
                                         (unsigned short*)gidxT32);
    table_kernel<<<(BT + 255) / 256, 256, 0, stream>>>(counts, off32, gidx16, tabJ);
    scatter_kernel<<<(BE + 255) / 256, 256, 0, stream>>>(gid, cursor, prank16);
    pool_kernel<<<BB * (CC / 2), 1024, 0, stream>>>(fe, prank16, gidxT32, tabJ, out);
}

// Round 15
// 74.917 us; speedup vs baseline: 1.1070x; 1.0518x over previous
//
#include <hip/hip_runtime.h>

// Problem constants (fixed by reference setup_inputs()).
#define BB 8
#define CC 256
#define EE 18000
#define TT 4500
#define BT (BB * TT)     // 36000
#define BE (BB * EE)     // 144000
#define NT 1024          // pool threads (16 waves); 73.8KB LDS -> 2 blocks/CU
#define GT (9 * 1024)    // u32 words per batch in transposed end-flag table

// ---------------- setup ----------------------------------------------------

// count + rank-in-group (atomic return value) in one pass
__global__ void count_kernel(const int* __restrict__ gid,
                             int* __restrict__ counts,
                             unsigned short* __restrict__ rkin16) {
    int i = blockIdx.x * blockDim.x + threadIdx.x;
    if (i < BE) {
        int b = i / EE;
        int rk = atomicAdd(&counts[b * TT + gid[i]], 1);
        rkin16[i] = (unsigned short)rk;
    }
}

// one block per batch, 256 threads, CHUNK=18: exclusive scan of counts ->
// off32 (group starts); gidx16[b*EE+ep] = g at group-end positions; the
// TRANSPOSED flag table gidxT16[((b*9 + ep%18/2)*1024 + ep/18)*2 + ep&1] =
// 0x8000|g (pool phase C reads it as coalesced u32).
__global__ __launch_bounds__(256) void scan_kernel(const int* __restrict__ counts,
                                                   int* __restrict__ off32,
                                                   unsigned short* __restrict__ gidx16,
                                                   unsigned short* __restrict__ gidxT16) {
    __shared__ int wsum[4];
    const int b  = blockIdx.x;
    const int t  = threadIdx.x;
    const int wv = t >> 6;
    const int ln = t & 63;
    const int lo = t * 18;

    int s = 0;
    if (lo < TT) {
        for (int j = 0; j < 18; ++j) s += counts[b * TT + lo + j];
    }
    int sc = s;
    for (int d = 1; d < 64; d <<= 1) {
        int o = __shfl_up(sc, d, 64);
        if (ln >= d) sc += o;
    }
    if (ln == 63) wsum[wv] = sc;
    __syncthreads();
    int cross = 0;
    for (int j = 0; j < 4; ++j) { int w = wsum[j]; if (j < wv) cross += w; }

    if (lo < TT) {
        int run = cross + (sc - s);               // exclusive prefix of group lo
        for (int j = 0; j < 18; ++j) {
            int g   = lo + j;
            int cnt = counts[b * TT + g];
            off32[b * TT + g] = run;
            int en = run + cnt;
            if (cnt) {
                int ep = en - 1;                  // end position of group g
                gidx16[b * EE + ep] = (unsigned short)g;
                int wt = ep / 18, k = ep % 18;
                gidxT16[((b * 9 + (k >> 1)) * 1024 + wt) * 2 + (k & 1)] =
                    (unsigned short)(0x8000u | (unsigned)g);
            }
            run = en;
        }
    }
}

// per-group epilogue table: tabJ[g] = {jprev (0xFFFF if start==0), bits(inv)}
// position st-1 is always a group-end => gidx16 lookup is always valid.
__global__ void table_kernel(const int* __restrict__ counts,
                             const int* __restrict__ off32,
                             const unsigned short* __restrict__ gidx16,
                             uint2* __restrict__ tabJ) {
    int i = blockIdx.x * blockDim.x + threadIdx.x;
    if (i < BT) {
        int b   = i / TT;
        int st  = off32[i];
        int cnt = counts[i];
        unsigned jp  = st ? (unsigned)gidx16[b * EE + st - 1] : 0xFFFFu;
        float    inv = cnt ? 1.0f / (float)cnt : 0.0f;
        tabJ[i] = make_uint2(jp, __float_as_uint(inv));
    }
}

// atomic-free CSR scatter: prank16[e] = off32[b,gid] + rank-in-group
__global__ void scatter_kernel(const int* __restrict__ gid,
                               const int* __restrict__ off32,
                               const unsigned short* __restrict__ rkin16,
                               unsigned short* __restrict__ prank16) {
    int i = blockIdx.x * blockDim.x + threadIdx.x;
    if (i < BE) {
        int b = i / EE;
        int p = off32[b * TT + gid[i]] + (int)rkin16[i];
        prank16[i] = (unsigned short)p;           // < 18000
    }
}

// ---------------- main: scatter + scan + compact-C + coalesced epilogue ----
// One block per (b,c), 1024 threads, 73.8KB LDS -> 2 blocks/CU = 32 waves.
// Scatter: 18000 random ds_write_b32 (unchanged, R11-proven). Phase A: 9x
// b64 reads -> all window values into pv regs. Phase C: 9 coalesced u32
// flag-table loads; write float prefix ONLY at the ~4500 group-end positions
// into compact C[g] aliasing vals[0..4499] (safe: values are in regs; writes
// happen after the wsum barrier, reads after the next). Epilogue: per 4
// consecutive groups: 1x b128 C read (coalesced), 4 near-coalesced jprev
// gathers, 1x float4 store. Threads 1000..1023: flag words are zero (memset;
// ep<18000) -> no stray writes; their wsum[15] garbage is never consumed.

__global__ __launch_bounds__(1024, 8) void pool_kernel(const float* __restrict__ fe,
                                                       const unsigned short* __restrict__ prank16,
                                                       const unsigned int* __restrict__ gidxT32,
                                                       const uint2* __restrict__ tabJ,
                                                       float* __restrict__ out) {
    __shared__ float vals[NT * 18];               // 73728 B; C[g] aliases [0..4499]
    __shared__ float wsum[16];
    const int b   = blockIdx.x >> 8;              // CC == 256
    const int c   = blockIdx.x & 255;
    const int tid = threadIdx.x;
    const int wv  = tid >> 6;
    const int ln  = tid & 63;

    // scatter row into CSR order (coalesced float4 + ushort4 reads)
    const float4*  fe4 = (const float4*)(fe + (size_t)(b * CC + c) * EE);
    const ushort4* rk4 = (const ushort4*)(prank16 + (size_t)b * EE);
#pragma unroll
    for (int i = 0; i < 5; ++i) {                 // 5*1024 = 5120 >= 4500
        int idx = tid + (i << 10);
        if (idx < EE / 4) {
            float4  v = fe4[idx];
            ushort4 r = rk4[idx];
            vals[r.x] = v.x;
            vals[r.y] = v.y;
            vals[r.z] = v.z;
            vals[r.w] = v.w;
        }
    }
    __syncthreads();

    // phase A: 9x b64 reads; pv[k] = {v_even, v_even + v_odd}
    const float2* smem2 = reinterpret_cast<const float2*>(vals);
    const int fbase = 9 * tid;                    // float2 index; 72B stride
    float2 pv[9];
#pragma unroll
    for (int k = 0; k < 9; ++k) {
        float2 v = smem2[fbase + k];
        pv[k] = make_float2(v.x, v.x + v.y);
    }
    float t01 = pv[0].y + pv[1].y, t23 = pv[2].y + pv[3].y;
    float t45 = pv[4].y + pv[5].y, t67 = pv[6].y + pv[7].y;
    const float sum = ((t01 + t23) + (t45 + t67)) + pv[8].y;

    // per-wave inclusive shfl scan of window sums
    float sc = sum;
#pragma unroll
    for (int d = 1; d < 64; d <<= 1) {
        float o = __shfl_up(sc, d, 64);
        if (ln >= d) sc += o;
    }
    if (ln == 63) wsum[wv] = sc;                  // wave total
    __syncthreads();

    float cross = 0.0f;
#pragma unroll
    for (int j = 0; j < 16; ++j) {
        float tw = wsum[j];                       // broadcast read
        if (j < wv) cross += tw;
    }

    // phase C: coalesced flag loads; masked compact end-prefix writes
    const unsigned int* gxT = gidxT32 + b * GT;
    float run = cross + (sc - sum);               // incl prefix up to window start
#pragma unroll
    for (int k = 0; k < 9; ++k) {
        unsigned w = gxT[(k << 10) + tid];        // lo16: pos 2k, hi16: pos 2k+1
        if (w & 0x8000u)     vals[w & 0x7fffu]         = run + pv[k].x;
        if (w & 0x80000000u) vals[(w >> 16) & 0x7fffu] = run + pv[k].y;
        run += pv[k].y;
    }
    __syncthreads();

    // epilogue: 4 consecutive groups per slot; b128 C read + jprev gathers
    const uint2* tb   = tabJ + b * TT;
    float*       outb = out + (size_t)(b * CC + c) * TT;
    for (int s = tid; s < TT / 4; s += NT) {      // 1125 slots
        int base4 = s << 2;
        uint4 qA = *reinterpret_cast<const uint4*>(tb + base4);      // jp0,iv0,jp1,iv1
        uint4 qB = *reinterpret_cast<const uint4*>(tb + base4 + 2);  // jp2,iv2,jp3,iv3

        float4 Cv = *reinterpret_cast<const float4*>(&vals[base4]);  // C[g..g+3]
        float B0 = (qA.x != 0xFFFFu) ? vals[qA.x] : 0.0f;
        float B1 = (qA.z != 0xFFFFu) ? vals[qA.z] : 0.0f;
        float B2 = (qB.x != 0xFFFFu) ? vals[qB.x] : 0.0f;
        float B3 = (qB.z != 0xFFFFu) ? vals[qB.z] : 0.0f;
        float iv0 = __uint_as_float(qA.y), iv1 = __uint_as_float(qA.w);
        float iv2 = __uint_as_float(qB.y), iv3 = __uint_as_float(qB.w);

        float4 o;
        o.x = (Cv.x - B0) * iv0;
        o.y = (Cv.y - B1) * iv1;
        o.z = (Cv.z - B2) * iv2;
        o.w = (Cv.w - B3) * iv3;
        *reinterpret_cast<float4*>(outb + base4) = o;
    }
}

extern "C" void kernel_launch(void* const* d_in, const int* in_sizes, int n_in,
                              void* d_out, int out_size, void* d_ws, size_t ws_size,
                              hipStream_t stream) {
    const float* fe  = (const float*)d_in[0];
    const int*   gid = (const int*)d_in[1];
    float*       out = (float*)d_out;

    // ws: counts[BT] i32 | gidxT32[BB*GT] u32 | off32[BT] i32 | tabJ[BT] uint2 |
    //     gidx16[BB*EE] u16 | rkin16[BE] u16 | prank16[BE] u16
    int*            counts  = (int*)d_ws;
    unsigned int*   gidxT32 = (unsigned int*)(counts + BT);
    int*            off32   = (int*)(gidxT32 + BB * GT);
    uint2*          tabJ    = (uint2*)(off32 + BT);
    unsigned short* gidx16  = (unsigned short*)(tabJ + BT);
    unsigned short* rkin16  = gidx16 + (size_t)BB * EE;
    unsigned short* prank16 = rkin16 + BE;

    // zero counts + flag table in one async memset (graph-capturable)
    hipMemsetAsync(d_ws, 0, (size_t)(BT + BB * GT) * 4, stream);
    count_kernel<<<(BE + 255) / 256, 256, 0, stream>>>(gid, counts, rkin16);
    scan_kernel<<<BB, 256, 0, stream>>>(counts, off32, gidx16,
                                        (unsigned short*)gidxT32);
    table_kernel<<<(BT + 255) / 256, 256, 0, stream>>>(counts, off32, gidx16, tabJ);
    scatter_kernel<<<(BE + 255) / 256, 256, 0, stream>>>(gid, off32, rkin16, prank16);
    pool_kernel<<<BB * CC, 1024, 0, stream>>>(fe, prank16, gidxT32, tabJ, out);
}

// Round 17
// 58.448 us; speedup vs baseline: 1.4190x; 1.2818x over previous
//
#include <hip/hip_runtime.h>

// Problem constants (fixed by reference setup_inputs()).
#define BB 8
#define CC 256
#define EE 18000
#define TT 4500
#define BT (BB * TT)     // 36000
#define BE (BB * EE)     // 144000
#define NT 1024          // pool threads (16 waves) -> 2 blocks/CU = 32 waves/CU
#define W  18            // positions per thread window
#define PW (NT * W)      // 18432 floats = 73728 B LDS

// ---------------- setup ----------------------------------------------------

__global__ void zero_counts_kernel(int* __restrict__ counts) {
    int i = blockIdx.x * blockDim.x + threadIdx.x;
    if (i < BT) counts[i] = 0;
}

// histogram + rank-in-group from the atomic return value
__global__ void count_kernel(const int* __restrict__ gid,
                             int* __restrict__ counts,
                             unsigned short* __restrict__ rkin16) {
    int i = blockIdx.x * blockDim.x + threadIdx.x;
    if (i < BE) {
        int b = i / EE;
        int rk = atomicAdd(&counts[b * TT + gid[i]], 1);
        rkin16[i] = (unsigned short)rk;
    }
}

// one block per batch, 256 threads: wave-scan of counts (250 threads x 18
// groups = 4500 exactly); writes off32 (group starts) and epilogue table
// tab[g] = {start | end<<16, bits(inv)} inline.
__global__ __launch_bounds__(256) void scan_kernel(const int* __restrict__ counts,
                                                   int* __restrict__ off32,
                                                   uint2* __restrict__ tab) {
    __shared__ int wtot[4];
    const int b  = blockIdx.x;
    const int t  = threadIdx.x;
    const int wv = t >> 6;
    const int ln = t & 63;
    const int lo = t * W;                         // 250 threads cover 4500

    int cnt[W];
    int s = 0;
    if (lo < TT) {
#pragma unroll
        for (int j = 0; j < W; ++j) { cnt[j] = counts[b * TT + lo + j]; s += cnt[j]; }
    }
    int sc = s;
#pragma unroll
    for (int d = 1; d < 64; d <<= 1) {
        int o = __shfl_up(sc, d, 64);
        if (ln >= d) sc += o;
    }
    if (ln == 63) wtot[wv] = sc;
    __syncthreads();
    int cross = 0;
#pragma unroll
    for (int j = 0; j < 4; ++j) { int w = wtot[j]; if (j < wv) cross += w; }

    if (lo < TT) {
        int run = cross + (sc - s);               // exclusive prefix of group lo
#pragma unroll
        for (int j = 0; j < W; ++j) {
            int g  = lo + j;
            int en = run + cnt[j];
            float inv = cnt[j] ? 1.0f / (float)cnt[j] : 0.0f;
            off32[b * TT + g] = run;
            tab[b * TT + g]   = make_uint2((unsigned)run | ((unsigned)en << 16),
                                           __float_as_uint(inv));
            run = en;
        }
    }
}

// atomic-free CSR scatter: prank16[e] = off32[b,gid] + rank-in-group
__global__ void scatter_kernel(const int* __restrict__ gid,
                               const int* __restrict__ off32,
                               const unsigned short* __restrict__ rkin16,
                               unsigned short* __restrict__ prank16) {
    int i = blockIdx.x * blockDim.x + threadIdx.x;
    if (i < BE) {
        int b = i / EE;
        prank16[i] = (unsigned short)(off32[b * TT + gid[i]] + (int)rkin16[i]);
    }
}

// ---------------- main: staged scatter + block scan + epilogue -------------
// One block per (b,c), 1024 threads, 73.8KB LDS -> 2 blocks/CU = 32 waves.
// Scatter phase stages ALL 5 iterations' fe4+rk4 loads into registers BEFORE
// any LDS write (10 back-to-back global loads in flight vs R11's ~2).
// Phase C writes through the float2 VIEW (smem2w[fbase+k]) — R16's failure
// was indexing the float array with a float2 index here.

__global__ __launch_bounds__(1024, 8) void pool_kernel(const float* __restrict__ fe,
                                                       const unsigned short* __restrict__ prank16,
                                                       const uint2* __restrict__ tab,
                                                       float* __restrict__ out) {
    __shared__ float vals[PW];                    // 73728 B
    __shared__ float wsum[16];
    const int b   = blockIdx.x >> 8;              // CC == 256
    const int c   = blockIdx.x & 255;
    const int tid = threadIdx.x;
    const int wv  = tid >> 6;
    const int ln  = tid & 63;

    // ---- scatter: stage all loads first, then all LDS writes ----
    const float4*  fe4 = (const float4*)(fe + (size_t)(b * CC + c) * EE);
    const ushort4* rk4 = (const ushort4*)(prank16 + (size_t)b * EE);
    float4  v[5];
    ushort4 r[5];
#pragma unroll
    for (int i = 0; i < 5; ++i) {                 // 5*1024 = 5120 >= 4500
        int idx = tid + (i << 10);
        if (idx < EE / 4) {
            v[i] = fe4[idx];
            r[i] = rk4[idx];
        }
    }
#pragma unroll
    for (int i = 0; i < 5; ++i) {
        int idx = tid + (i << 10);
        if (idx < EE / 4) {
            vals[r[i].x] = v[i].x;
            vals[r[i].y] = v[i].y;
            vals[r[i].z] = v[i].z;
            vals[r[i].w] = v[i].w;
        }
    }
    __syncthreads();

    // phase A: 9x b64 loads; pv[k] = {v_even, chunk-inclusive prefix}
    const float2* smem2 = reinterpret_cast<const float2*>(vals);
    const int fbase = 9 * tid;                    // float2 index; 72B stride
    float2 pv[9];
#pragma unroll
    for (int k = 0; k < 9; ++k) {
        float2 vv = smem2[fbase + k];
        pv[k] = make_float2(vv.x, vv.x + vv.y);
    }
    float t01 = pv[0].y + pv[1].y, t23 = pv[2].y + pv[3].y;
    float t45 = pv[4].y + pv[5].y, t67 = pv[6].y + pv[7].y;
    const float sum = ((t01 + t23) + (t45 + t67)) + pv[8].y;

    // per-wave inclusive shfl scan of window sums
    float sc = sum;
#pragma unroll
    for (int d = 1; d < 64; d <<= 1) {
        float o = __shfl_up(sc, d, 64);
        if (ln >= d) sc += o;
    }
    if (ln == 63) wsum[wv] = sc;                  // wave total
    __syncthreads();

    // cross-wave exclusive offset
    float cross = 0.0f;
#pragma unroll
    for (int j = 0; j < 16; ++j) {
        float tw = wsum[j];                       // broadcast read
        if (j < wv) cross += tw;
    }

    // phase C: add running offset, 9x b64 stores through the float2 view
    float2* smem2w = reinterpret_cast<float2*>(vals);
    float off = cross + (sc - sum);               // exclusive prefix of window
#pragma unroll
    for (int k = 0; k < 9; ++k) {
        float2 p = pv[k];
        smem2w[fbase + k] = make_float2(p.x + off, p.y + off);
        off += p.y;                               // chunk sum
    }
    __syncthreads();

    // epilogue: 4 consecutive groups per slot; chained prefix reads
    const uint2* tbB  = tab + b * TT;
    float*       outb = out + (size_t)(b * CC + c) * TT;
    for (int s = tid; s < TT / 4; s += NT) {      // 1125 slots
        const uint2* tb = tbB + (s << 2);
        uint4 qA = *reinterpret_cast<const uint4*>(tb);      // groups 4s,4s+1
        uint4 qB = *reinterpret_cast<const uint4*>(tb + 2);  // groups 4s+2,4s+3

        unsigned se0 = qA.x, se1 = qA.z, se2 = qB.x, se3 = qB.z;
        float iv0 = __uint_as_float(qA.y), iv1 = __uint_as_float(qA.w);
        float iv2 = __uint_as_float(qB.y), iv3 = __uint_as_float(qB.w);

        unsigned st0 = se0 & 0xffffu;
        unsigned en0 = se0 >> 16, en1 = se1 >> 16, en2 = se2 >> 16, en3 = se3 >> 16;

        // P(pos) = pos ? vals[pos-1] : 0; reads clamped to valid range
        float Pp = vals[(st0 ? st0 : 1u) - 1u]; Pp = st0 ? Pp : 0.0f;
        float P0 = vals[(en0 ? en0 : 1u) - 1u]; P0 = en0 ? P0 : 0.0f;
        float P1 = vals[(en1 ? en1 : 1u) - 1u]; P1 = en1 ? P1 : 0.0f;
        float P2 = vals[(en2 ? en2 : 1u) - 1u]; P2 = en2 ? P2 : 0.0f;
        float P3 = vals[(en3 ? en3 : 1u) - 1u]; P3 = en3 ? P3 : 0.0f;

        float4 o;
        o.x = (P0 - Pp) * iv0;                    // st(g+1) == en(g): chain
        o.y = (P1 - P0) * iv1;
        o.z = (P2 - P1) * iv2;
        o.w = (P3 - P2) * iv3;

        *reinterpret_cast<float4*>(outb + (s << 2)) = o;
    }
}

extern "C" void kernel_launch(void* const* d_in, const int* in_sizes, int n_in,
                              void* d_out, int out_size, void* d_ws, size_t ws_size,
                              hipStream_t stream) {
    const float* fe  = (const float*)d_in[0];
    const int*   gid = (const int*)d_in[1];
    float*       out = (float*)d_out;

    // ws: counts[BT] i32 | off32[BT] i32 | tab[BT] uint2 | rkin16[BE] u16 | prank16[BE] u16
    int*            counts  = (int*)d_ws;
    int*            off32   = counts + BT;
    uint2*          tab     = (uint2*)(off32 + BT);    // 8B-aligned
    unsigned short* rkin16  = (unsigned short*)(tab + BT);
    unsigned short* prank16 = rkin16 + BE;

    zero_counts_kernel<<<(BT + 255) / 256, 256, 0, stream>>>(counts);
    count_kernel<<<(BE + 255) / 256, 256, 0, stream>>>(gid, counts, rkin16);
    scan_kernel<<<BB, 256, 0, stream>>>(counts, off32, tab);
    scatter_kernel<<<(BE + 255) / 256, 256, 0, stream>>>(gid, off32, rkin16, prank16);
    pool_kernel<<<BB * CC, 1024, 0, stream>>>(fe, prank16, tab, out);
}

// Round 18
// 57.321 us; speedup vs baseline: 1.4469x; 1.0197x over previous
//
#include <hip/hip_runtime.h>

// Problem constants (fixed by reference setup_inputs()).
#define BB 8
#define CC 256
#define EE 18000
#define TT 4500
#define BT (BB * TT)     // 36000
#define BE (BB * EE)     // 144000
#define NT 1024          // pool threads (16 waves) -> 2 blocks/CU = 32 waves/CU
#define W  18            // positions per thread window
#define PW (NT * W)      // 18432 floats = 73728 B LDS

// ---------------- setup ----------------------------------------------------

__global__ void zero_counts_kernel(int* __restrict__ counts) {
    int i = blockIdx.x * blockDim.x + threadIdx.x;
    if (i < BT) counts[i] = 0;
}

// histogram + rank-in-group from the atomic return value
__global__ void count_kernel(const int* __restrict__ gid,
                             int* __restrict__ counts,
                             unsigned short* __restrict__ rkin16) {
    int i = blockIdx.x * blockDim.x + threadIdx.x;
    if (i < BE) {
        int b = i / EE;
        int rk = atomicAdd(&counts[b * TT + gid[i]], 1);
        rkin16[i] = (unsigned short)rk;
    }
}

// one block per batch, 256 threads: wave-scan of counts (250 threads x 18
// groups = 4500 exactly); writes off32 (group starts) and epilogue table
// tab[g] = {start | end<<16, bits(inv)} inline.
__global__ __launch_bounds__(256) void scan_kernel(const int* __restrict__ counts,
                                                   int* __restrict__ off32,
                                                   uint2* __restrict__ tab) {
    __shared__ int wtot[4];
    const int b  = blockIdx.x;
    const int t  = threadIdx.x;
    const int wv = t >> 6;
    const int ln = t & 63;
    const int lo = t * W;                         // 250 threads cover 4500

    int cnt[W];
    int s = 0;
    if (lo < TT) {
#pragma unroll
        for (int j = 0; j < W; ++j) { cnt[j] = counts[b * TT + lo + j]; s += cnt[j]; }
    }
    int sc = s;
#pragma unroll
    for (int d = 1; d < 64; d <<= 1) {
        int o = __shfl_up(sc, d, 64);
        if (ln >= d) sc += o;
    }
    if (ln == 63) wtot[wv] = sc;
    __syncthreads();
    int cross = 0;
#pragma unroll
    for (int j = 0; j < 4; ++j) { int w = wtot[j]; if (j < wv) cross += w; }

    if (lo < TT) {
        int run = cross + (sc - s);               // exclusive prefix of group lo
#pragma unroll
        for (int j = 0; j < W; ++j) {
            int g  = lo + j;
            int en = run + cnt[j];
            float inv = cnt[j] ? 1.0f / (float)cnt[j] : 0.0f;
            off32[b * TT + g] = run;
            tab[b * TT + g]   = make_uint2((unsigned)run | ((unsigned)en << 16),
                                           __float_as_uint(inv));
            run = en;
        }
    }
}

// atomic-free CSR scatter: prank16[e] = off32[b,gid] + rank-in-group
__global__ void scatter_kernel(const int* __restrict__ gid,
                               const int* __restrict__ off32,
                               const unsigned short* __restrict__ rkin16,
                               unsigned short* __restrict__ prank16) {
    int i = blockIdx.x * blockDim.x + threadIdx.x;
    if (i < BE) {
        int b = i / EE;
        prank16[i] = (unsigned short)(off32[b * TT + gid[i]] + (int)rkin16[i]);
    }
}

// ---------------- main: 2 sequential channel passes per block --------------
// One block per (b, channel-pair), 1024 threads, 73.8KB LDS -> 2 blocks/CU.
// rank16 is staged into r[5] registers ONCE and reused by both passes
// (halves rank16 global traffic + address VALU); tab's second read is
// L2-hot; block count halves. Each pass is R17-verbatim: staged fe loads,
// scatter, b64 scan phases (phase C via the float2 VIEW), chained epilogue.

__global__ __launch_bounds__(1024, 8) void pool_kernel(const float* __restrict__ fe,
                                                       const unsigned short* __restrict__ prank16,
                                                       const uint2* __restrict__ tab,
                                                       float* __restrict__ out) {
    __shared__ float vals[PW];                    // 73728 B
    __shared__ float wsum[16];
    const int b   = blockIdx.x >> 7;              // 128 channel-pairs per batch
    const int c0  = (blockIdx.x & 127) << 1;
    const int tid = threadIdx.x;
    const int wv  = tid >> 6;
    const int ln  = tid & 63;

    // stage rank once; reused by both passes
    const ushort4* rk4 = (const ushort4*)(prank16 + (size_t)b * EE);
    ushort4 r[5];
#pragma unroll
    for (int i = 0; i < 5; ++i) {                 // 5*1024 = 5120 >= 4500
        int idx = tid + (i << 10);
        if (idx < EE / 4) r[i] = rk4[idx];
    }

    const uint2* tbB = tab + b * TT;

#pragma unroll
    for (int pass = 0; pass < 2; ++pass) {
        const int c = c0 + pass;

        // ---- scatter: stage fe loads first, then all LDS writes ----
        const float4* fe4 = (const float4*)(fe + (size_t)(b * CC + c) * EE);
        float4 v[5];
#pragma unroll
        for (int i = 0; i < 5; ++i) {
            int idx = tid + (i << 10);
            if (idx < EE / 4) v[i] = fe4[idx];
        }
#pragma unroll
        for (int i = 0; i < 5; ++i) {
            int idx = tid + (i << 10);
            if (idx < EE / 4) {
                vals[r[i].x] = v[i].x;
                vals[r[i].y] = v[i].y;
                vals[r[i].z] = v[i].z;
                vals[r[i].w] = v[i].w;
            }
        }
        __syncthreads();

        // phase A: 9x b64 loads; pv[k] = {v_even, chunk-inclusive prefix}
        const float2* smem2 = reinterpret_cast<const float2*>(vals);
        const int fbase = 9 * tid;                // float2 index; 72B stride
        float2 pv[9];
#pragma unroll
        for (int k = 0; k < 9; ++k) {
            float2 vv = smem2[fbase + k];
            pv[k] = make_float2(vv.x, vv.x + vv.y);
        }
        float t01 = pv[0].y + pv[1].y, t23 = pv[2].y + pv[3].y;
        float t45 = pv[4].y + pv[5].y, t67 = pv[6].y + pv[7].y;
        const float sum = ((t01 + t23) + (t45 + t67)) + pv[8].y;

        // per-wave inclusive shfl scan of window sums
        float sc = sum;
#pragma unroll
        for (int d = 1; d < 64; d <<= 1) {
            float o = __shfl_up(sc, d, 64);
            if (ln >= d) sc += o;
        }
        if (ln == 63) wsum[wv] = sc;              // wave total
        __syncthreads();

        // cross-wave exclusive offset
        float cross = 0.0f;
#pragma unroll
        for (int j = 0; j < 16; ++j) {
            float tw = wsum[j];                   // broadcast read
            if (j < wv) cross += tw;
        }

        // phase C: add running offset, 9x b64 stores through the float2 view
        float2* smem2w = reinterpret_cast<float2*>(vals);
        float off = cross + (sc - sum);           // exclusive prefix of window
#pragma unroll
        for (int k = 0; k < 9; ++k) {
            float2 p = pv[k];
            smem2w[fbase + k] = make_float2(p.x + off, p.y + off);
            off += p.y;                           // chunk sum
        }
        __syncthreads();

        // epilogue: 4 consecutive groups per slot; chained prefix reads
        float* outb = out + (size_t)(b * CC + c) * TT;
        for (int s = tid; s < TT / 4; s += NT) {  // 1125 slots
            const uint2* tb = tbB + (s << 2);
            uint4 qA = *reinterpret_cast<const uint4*>(tb);      // groups 4s,4s+1
            uint4 qB = *reinterpret_cast<const uint4*>(tb + 2);  // groups 4s+2,4s+3

            unsigned se0 = qA.x, se1 = qA.z, se2 = qB.x, se3 = qB.z;
            float iv0 = __uint_as_float(qA.y), iv1 = __uint_as_float(qA.w);
            float iv2 = __uint_as_float(qB.y), iv3 = __uint_as_float(qB.w);

            unsigned st0 = se0 & 0xffffu;
            unsigned en0 = se0 >> 16, en1 = se1 >> 16, en2 = se2 >> 16, en3 = se3 >> 16;

            // P(pos) = pos ? vals[pos-1] : 0; reads clamped to valid range
            float Pp = vals[(st0 ? st0 : 1u) - 1u]; Pp = st0 ? Pp : 0.0f;
            float P0 = vals[(en0 ? en0 : 1u) - 1u]; P0 = en0 ? P0 : 0.0f;
            float P1 = vals[(en1 ? en1 : 1u) - 1u]; P1 = en1 ? P1 : 0.0f;
            float P2 = vals[(en2 ? en2 : 1u) - 1u]; P2 = en2 ? P2 : 0.0f;
            float P3 = vals[(en3 ? en3 : 1u) - 1u]; P3 = en3 ? P3 : 0.0f;

            float4 o;
            o.x = (P0 - Pp) * iv0;                // st(g+1) == en(g): chain
            o.y = (P1 - P0) * iv1;
            o.z = (P2 - P1) * iv2;
            o.w = (P3 - P2) * iv3;

            *reinterpret_cast<float4*>(outb + (s << 2)) = o;
        }
        __syncthreads();                          // protect vals before next pass
    }
}

extern "C" void kernel_launch(void* const* d_in, const int* in_sizes, int n_in,
                              void* d_out, int out_size, void* d_ws, size_t ws_size,
                              hipStream_t stream) {
    const float* fe  = (const float*)d_in[0];
    const int*   gid = (const int*)d_in[1];
    float*       out = (float*)d_out;

    // ws: counts[BT] i32 | off32[BT] i32 | tab[BT] uint2 | rkin16[BE] u16 | prank16[BE] u16
    int*            counts  = (int*)d_ws;
    int*            off32   = counts + BT;
    uint2*          tab     = (uint2*)(off32 + BT);    // 8B-aligned
    unsigned short* rkin16  = (unsigned short*)(tab + BT);
    unsigned short* prank16 = rkin16 + BE;

    zero_counts_kernel<<<(BT + 255) / 256, 256, 0, stream>>>(counts);
    count_kernel<<<(BE + 255) / 256, 256, 0, stream>>>(gid, counts, rkin16);
    scan_kernel<<<BB, 256, 0, stream>>>(counts, off32, tab);
    scatter_kernel<<<(BE + 255) / 256, 256, 0, stream>>>(gid, off32, rkin16, prank16);
    pool_kernel<<<BB * (CC / 2), 1024, 0, stream>>>(fe, prank16, tab, out);
}